// Round 2
// baseline (240.010 us; speedup 1.0000x reference)
//
#include <hip/hip_runtime.h>

typedef short  s16x8  __attribute__((ext_vector_type(8)));
typedef float  f32x16 __attribute__((ext_vector_type(16)));
typedef unsigned short u16;
typedef unsigned long long u64b;

#define MFMA32(a,b,c) __builtin_amdgcn_mfma_f32_32x32x16_bf16((a),(b),(c),0,0,0)
#define KCLS 100

__device__ __forceinline__ u16 f2bf(float f) {
  unsigned u = __builtin_bit_cast(unsigned, f);
  u += 0x7fffu + ((u >> 16) & 1u);   // RNE
  return (u16)(u >> 16);
}

__device__ __forceinline__ float tanh_fast(float x) {
  float e = __builtin_amdgcn_exp2f(x * 2.8853900817779268f);
  return 1.0f - 2.0f * __builtin_amdgcn_rcpf(e + 1.0f);
}

__device__ __forceinline__ void ld_lds16(const void* g, void* l) {
  __builtin_amdgcn_global_load_lds(
      (const __attribute__((address_space(1))) unsigned char*)g,
      (__attribute__((address_space(3))) unsigned char*)l, 16, 0, 0);
}

// ---------- prep: W fp32->bf16 convert  +  x [B,C,P] -> xT [B,P,C] bf16 ----------
__global__ void prep(const float* __restrict__ w1, const float* __restrict__ w2,
                     const float* __restrict__ w3, const float* __restrict__ x,
                     u16* __restrict__ o1, u16* __restrict__ o2, u16* __restrict__ o3,
                     u16* __restrict__ xT) {
  __shared__ float tile[64][68];
  int bid = blockIdx.x;
  if (bid < 4400) {
    int i = bid * 256 + threadIdx.x;           // float4 index
    const float* src; u16* dst; int j;
    if (i < 819200)        { src = w1; dst = o1; j = i; }
    else if (i < 1024000)  { src = w2; dst = o2; j = i - 819200; }
    else                   { src = w3; dst = o3; j = i - 1024000; }
    float4 v = *(const float4*)(src + (size_t)j * 4);
    u16 o[4] = { f2bf(v.x), f2bf(v.y), f2bf(v.z), f2bf(v.w) };
    *(u64b*)(dst + (size_t)j * 4) = *(u64b*)o;
  } else {
    int idx = bid - 4400;
    int b = idx >> 3, c0 = (idx & 7) * 64;
    for (int i = threadIdx.x; i < 64 * 16; i += 256) {
      int r = i >> 4, s = i & 15;
      float4 v = *(const float4*)(x + ((size_t)b * 512 + c0 + r) * 64 + s * 4);
      tile[r][s * 4 + 0] = v.x; tile[r][s * 4 + 1] = v.y;
      tile[r][s * 4 + 2] = v.z; tile[r][s * 4 + 3] = v.w;
    }
    __syncthreads();
    for (int i = threadIdx.x; i < 64 * 8; i += 256) {
      int p = i >> 3, sg = i & 7;
      u16 o[8];
      #pragma unroll
      for (int j = 0; j < 8; j++) o[j] = f2bf(tile[sg * 8 + j][p]);
      *(uint4*)(xT + ((size_t)b * 64 + p) * 512 + c0 + sg * 8) = *(uint4*)o;
    }
  }
}

// ---------- main: per-(k, b-pair) encoder chain + distances ----------
// Fragment-order LDS everywhere: frag = [64 lanes][8 bf16] = 1 KB, reads are
// ds_read_b128 at base+lane*16 (conflict-free).
__global__ __launch_bounds__(256, 3) void cssr_main(
    const u16* __restrict__ W1b, const u16* __restrict__ W2b, const u16* __restrict__ W3b,
    const u16* __restrict__ xT, const float* __restrict__ protos,
    const float* __restrict__ protos1, float* __restrict__ out,
    float* __restrict__ fw, float* __restrict__ f1w)
{
  __shared__ u16 regionA[2][16][64][8];   // x dbuf (2 x 16 frags); later h2frag (32 frags)
  __shared__ u16 regionB[16][64][8];      // h1frag (16 frags)
  __shared__ float red[8];
  u16 (*h2f)[64][8] = (u16(*)[64][8])&regionA[0][0][0][0];

  const int bid = blockIdx.x;
  const int k = bid >> 5, bg = bid & 31;
  const int b0 = bg * 2;
  const int tid = threadIdx.x, w = tid >> 6, lane = tid & 63;
  const int nhalf = lane >> 5, nn = lane & 31;
  const int mt = w >> 1, ntp = w & 1;     // wave tile coords (2x2 grid)

  // ---------------- stage 1: h1 = tanh(W1[k] @ x[b0..b0+1])  M=64 N=128 K=512 ----
  // n-tile nt in [0,4): b = b0+(nt>>1), p-half = nt&1. Chunk = 64 c (4 k-steps).
  {
    #pragma unroll
    for (int i = 0; i < 4; i++) {         // preload chunk 0; wave w stages ksl=w
      int nt = i;
      const u16* gp = xT + ((size_t)((b0 + (nt >> 1)) * 64 + (nt & 1) * 32 + nn)) * 512
                      + w * 16 + nhalf * 8;
      ld_lds16(gp, &regionA[0][w * 4 + i][0][0]);
    }
  }
  __syncthreads();

  f32x16 acc1[2] = {};
  const u16* Abase = W1b + ((size_t)k * 64 + mt * 32 + nn) * 512 + nhalf * 8;
  for (int ck = 0; ck < 8; ck++) {
    int pb = ck & 1;
    if (ck < 7) {
      #pragma unroll
      for (int i = 0; i < 4; i++) {
        int nt = i;
        const u16* gp = xT + ((size_t)((b0 + (nt >> 1)) * 64 + (nt & 1) * 32 + nn)) * 512
                        + (ck + 1) * 64 + w * 16 + nhalf * 8;
        ld_lds16(gp, &regionA[pb ^ 1][w * 4 + i][0][0]);
      }
    }
    #pragma unroll
    for (int ksl = 0; ksl < 4; ksl++) {
      s16x8 A = *(const s16x8*)(Abase + ck * 64 + ksl * 16);
      #pragma unroll
      for (int ntl = 0; ntl < 2; ntl++) {
        s16x8 B = *(const s16x8*)&regionA[pb][ksl * 4 + ntp * 2 + ntl][lane][0];
        acc1[ntl] = MFMA32(A, B, acc1[ntl]);
      }
    }
    __syncthreads();
  }

  // handoff: C/D (m=(q+8g+4h), n) -> stage2 B-frag [kb][lane=(g&1)*32+n][j=q+4h]
  #pragma unroll
  for (int ntl = 0; ntl < 2; ntl++) {
    int nt = ntp * 2 + ntl;
    #pragma unroll
    for (int g = 0; g < 4; g++) {
      u16 hv[4];
      #pragma unroll
      for (int q = 0; q < 4; q++) hv[q] = f2bf(tanh_fast(acc1[ntl][g * 4 + q]));
      int kbg = mt * 2 + (g >> 1);
      int tl  = (g & 1) * 32 + nn;
      *(u64b*)&regionB[kbg * 4 + nt][tl][nhalf * 4] = *(u64b*)hv;
    }
  }
  __syncthreads();

  // ---------------- stage 2: h2 = tanh(W2[k] @ h1)  M=128 N=128 K=64 ----------
  f32x16 acc2[2][2] = {};
  #pragma unroll
  for (int kb = 0; kb < 4; kb++) {
    s16x8 A0 = *(const s16x8*)(W2b + ((size_t)k * 128 + (mt * 2 + 0) * 32 + nn) * 64 + kb * 16 + nhalf * 8);
    s16x8 A1 = *(const s16x8*)(W2b + ((size_t)k * 128 + (mt * 2 + 1) * 32 + nn) * 64 + kb * 16 + nhalf * 8);
    #pragma unroll
    for (int ntl = 0; ntl < 2; ntl++) {
      s16x8 B = *(const s16x8*)&regionB[kb * 4 + ntp * 2 + ntl][lane][0];
      acc2[0][ntl] = MFMA32(A0, B, acc2[0][ntl]);
      acc2[1][ntl] = MFMA32(A1, B, acc2[1][ntl]);
    }
  }
  // handoff into h2frag (aliases regionA; all stage-1 reads completed pre-barrier)
  #pragma unroll
  for (int i = 0; i < 2; i++) {
    #pragma unroll
    for (int ntl = 0; ntl < 2; ntl++) {
      int nt = ntp * 2 + ntl;
      #pragma unroll
      for (int g = 0; g < 4; g++) {
        u16 hv[4];
        #pragma unroll
        for (int q = 0; q < 4; q++) hv[q] = f2bf(tanh_fast(acc2[i][ntl][g * 4 + q]));
        int kbg2 = (mt * 2 + i) * 2 + (g >> 1);
        int tl   = (g & 1) * 32 + nn;
        *(u64b*)&h2f[kbg2 * 4 + nt][tl][nhalf * 4] = *(u64b*)hv;
      }
    }
  }
  __syncthreads();

  // ---------------- stage 3: lt = tanh(W3[k] @ h2)  M=32 N=128 K=128 ----------
  // wave w owns n-tile nt=w (b = b0+(w>>1), p-half = w&1), full K
  f32x16 acc3 = {};
  #pragma unroll
  for (int kb = 0; kb < 8; kb++) {
    s16x8 A = *(const s16x8*)(W3b + ((size_t)k * 32 + nn) * 128 + kb * 16 + nhalf * 8);
    s16x8 B = *(const s16x8*)&h2f[kb * 4 + w][lane][0];
    acc3 = MFMA32(A, B, acc3);
  }

  // ---------------- distances, clip, logits, f / f1 ----------------
  const int b = b0 + (w >> 1);
  const int p = (w & 1) * 32 + nn;
  const float* pr  = protos  + (size_t)k * 2048;
  const float* pr1 = protos1 + (size_t)k * 2048;
  float d2 = 0.f, d21 = 0.f;
  #pragma unroll
  for (int g = 0; g < 4; g++) {
    #pragma unroll
    for (int q = 0; q < 4; q++) {
      int m = q + 8 * g + 4 * nhalf;
      float lt = tanh_fast(acc3[g * 4 + q]);
      float d = lt - pr [m * 64 + p];  d2  += d * d;
      float e = lt - pr1[m * 64 + p];  d21 += e * e;
    }
  }
  d2 += __shfl_xor(d2, 32); d21 += __shfl_xor(d21, 32);
  float er  = fminf(fmaxf(d2  * -0.1f, -100.f), 100.f);
  float er1 = fminf(fmaxf(d21 * -0.1f, -100.f), 100.f);
  if (nhalf == 0) {
    out[(size_t)b * 6400 + k * 64 + p]          = er;
    out[409600 + (size_t)b * 6400 + k * 64 + p] = er1;
  }
  float s = er, s1 = er1;
  s += __shfl_xor(s, 1);  s1 += __shfl_xor(s1, 1);
  s += __shfl_xor(s, 2);  s1 += __shfl_xor(s1, 2);
  s += __shfl_xor(s, 4);  s1 += __shfl_xor(s1, 4);
  s += __shfl_xor(s, 8);  s1 += __shfl_xor(s1, 8);
  s += __shfl_xor(s, 16); s1 += __shfl_xor(s1, 16);
  if (lane == 0) { red[w] = s; red[4 + w] = s1; }
  __syncthreads();
  if (tid < 2)      fw [k * 64 + b0 + tid]      = red[tid * 2] + red[tid * 2 + 1];
  else if (tid < 4) f1w[k * 64 + b0 + (tid - 2)] = red[4 + (tid - 2) * 2] + red[5 + (tid - 2) * 2];
}

// ---------- finalize: pull / push scalars ----------
__global__ void finalize(const float* __restrict__ f, const float* __restrict__ f1,
                         const int* __restrict__ ycls, float* __restrict__ out2) {
  __shared__ float rp[128], rq[128];
  int t = threadIdx.x;
  float pullk = 0.f, pushk = 0.f;
  if (t < KCLS) {
    int neq = 0, nc = 0; float s1 = 0.f, s = 0.f;
    for (int b = 0; b < 64; b++) {
      float fv  = f [t * 64 + b];
      float f1v = f1[t * 64 + b];
      if (ycls[b] == t)      { neq++; s1 += f1v; }
      else if (fv < 10000.f) { nc++;  s  += fv; }
    }
    if (neq > 0) pullk = s1 / (float)neq;
    if (nc  > 0) pushk = s  / (float)nc;
  }
  rp[t] = pullk; rq[t] = pushk;
  __syncthreads();
  for (int off = 64; off > 0; off >>= 1) {
    if (t < off) { rp[t] += rp[t + off]; rq[t] += rq[t + off]; }
    __syncthreads();
  }
  if (t == 0) { out2[0] = rp[0]; out2[1] = rq[0]; }
}

extern "C" void kernel_launch(void* const* d_in, const int* in_sizes, int n_in,
                              void* d_out, int out_size, void* d_ws, size_t ws_size,
                              hipStream_t stream) {
  const float* x     = (const float*)d_in[0];
  const int*   ycls  = (const int*)d_in[1];
  const float* W1    = (const float*)d_in[4];
  const float* W2    = (const float*)d_in[5];
  const float* W3    = (const float*)d_in[6];
  const float* prot  = (const float*)d_in[7];
  const float* prot1 = (const float*)d_in[8];
  float* out = (float*)d_out;

  char* ws = (char*)d_ws;
  u16*  xTb = (u16*)(ws);                        // 4,194,304 B
  u16*  W1b = (u16*)(ws + 4194304);              // 6,553,600 B
  u16*  W2b = (u16*)(ws + 10747904);             // 1,638,400 B
  u16*  W3b = (u16*)(ws + 12386304);             //   819,200 B
  float* fw  = (float*)(ws + 13205504);          // 25,600 B
  float* f1w = (float*)(ws + 13231104);          // 25,600 B

  prep<<<4912, 256, 0, stream>>>(W1, W2, W3, x, W1b, W2b, W3b, xTb);
  cssr_main<<<KCLS * 32, 256, 0, stream>>>(W1b, W2b, W3b, xTb, prot, prot1, out, fw, f1w);
  finalize<<<1, 128, 0, stream>>>(fw, f1w, ycls, out + 819200);
}

// Round 3
// 161.755 us; speedup vs baseline: 1.4838x; 1.4838x over previous
//
#include <hip/hip_runtime.h>

typedef short  s16x8  __attribute__((ext_vector_type(8)));
typedef float  f32x16 __attribute__((ext_vector_type(16)));
typedef unsigned short u16;
typedef unsigned long long u64b;

#define MFMA32(a,b,c) __builtin_amdgcn_mfma_f32_32x32x16_bf16((a),(b),(c),0,0,0)
#define KCLS 100

__device__ __forceinline__ u16 f2bf(float f) {
  unsigned u = __builtin_bit_cast(unsigned, f);
  u += 0x7fffu + ((u >> 16) & 1u);   // RNE
  return (u16)(u >> 16);
}

__device__ __forceinline__ float tanh_fast(float x) {
  float e = __builtin_amdgcn_exp2f(x * 2.8853900817779268f);
  return 1.0f - 2.0f * __builtin_amdgcn_rcpf(e + 1.0f);
}

__device__ __forceinline__ void ld_lds16(const void* g, void* l) {
  __builtin_amdgcn_global_load_lds(
      (const __attribute__((address_space(1))) unsigned char*)g,
      (__attribute__((address_space(3))) unsigned char*)l, 16, 0, 0);
}

// ============ prep: emit fragment-ordered bf16 tensors ============
// Fragment = 1 KB: [lane64][8 bf16]; lane&31 = row/col-in-tile, lane>>5 = k-half.
// xF  [b][frag = (ck*4+ksl)*2+ph]      (64 frags/b,  p = ph*32+nn, c = ck*64+ksl*16+nhalf*8+j)
// W1F [k][frag = (ck*4+ksl)*2+mt]      (64 frags/k,  m = mt*32+nn, c as above)
// W2F [k][frag = kb*4+m4]              (16 frags/k,  m = m4*32+nn, c = kb*16+nhalf*8+j)
// W3F [k][frag = kb]                   ( 8 frags/k,  m = nn,       c = kb*16+nhalf*8+j)
__global__ void prep(const float* __restrict__ x, const float* __restrict__ w1,
                     const float* __restrict__ w2, const float* __restrict__ w3,
                     u16* __restrict__ xF, u16* __restrict__ W1F,
                     u16* __restrict__ W2F, u16* __restrict__ W3F) {
  __shared__ float tile[64][65];
  const int bid = blockIdx.x, t = threadIdx.x;
  if (bid < 64) {                       // ---- x: [C,P] -> frag order ----
    const int b = bid;
    for (int ck = 0; ck < 8; ck++) {
      #pragma unroll
      for (int j = 0; j < 4; j++) {     // coalesced fp32 tile load (64c x 64p)
        int e4 = j * 1024 + t * 4;
        int c = e4 >> 6, p0 = e4 & 63;
        float4 v = *(const float4*)(x + ((size_t)b * 512 + ck * 64 + c) * 64 + p0);
        tile[c][p0] = v.x; tile[c][p0 + 1] = v.y; tile[c][p0 + 2] = v.z; tile[c][p0 + 3] = v.w;
      }
      __syncthreads();
      #pragma unroll
      for (int i = 0; i < 2; i++) {     // 512 16B-slots
        int s = i * 256 + t;
        int ksl = s >> 7, ph = (s >> 6) & 1, lane = s & 63;
        int cb = ksl * 16 + (lane >> 5) * 8, pp = ph * 32 + (lane & 31);
        u16 o[8];
        #pragma unroll
        for (int jj = 0; jj < 8; jj++) o[jj] = f2bf(tile[cb + jj][pp]);
        *(uint4*)(xF + (((size_t)b * 64 + (ck * 4 + ksl) * 2 + ph) * 512) + lane * 8) = *(uint4*)o;
      }
      __syncthreads();
    }
  } else if (bid < 164) {               // ---- W1 ----
    const int k = bid - 64;
    #pragma unroll
    for (int i = 0; i < 16; i++) {
      int s = i * 256 + t;              // 4096 16B-slots
      int frag = s >> 6, lane = s & 63;
      int mt = frag & 1, ksl = (frag >> 1) & 3, ck = frag >> 3;
      int m = mt * 32 + (lane & 31), c0 = ck * 64 + ksl * 16 + (lane >> 5) * 8;
      const float* src = w1 + ((size_t)k * 64 + m) * 512 + c0;
      float4 a = *(const float4*)src, b4 = *(const float4*)(src + 4);
      u16 o[8] = { f2bf(a.x), f2bf(a.y), f2bf(a.z), f2bf(a.w),
                   f2bf(b4.x), f2bf(b4.y), f2bf(b4.z), f2bf(b4.w) };
      *(uint4*)(W1F + (((size_t)k * 64 + frag) * 512) + lane * 8) = *(uint4*)o;
    }
  } else {                              // ---- W2 + W3 ----
    const int k = bid - 164;
    #pragma unroll
    for (int i = 0; i < 6; i++) {
      int s = i * 256 + t;              // 1024 W2 slots + 512 W3 slots
      const float* src; u16* dst;
      if (s < 1024) {
        int frag = s >> 6, lane = s & 63;
        int kb = frag >> 2, m4 = frag & 3;
        int m = m4 * 32 + (lane & 31), c0 = kb * 16 + (lane >> 5) * 8;
        src = w2 + ((size_t)k * 128 + m) * 64 + c0;
        dst = W2F + (((size_t)k * 16 + frag) * 512) + lane * 8;
      } else {
        int s3 = s - 1024, kb = s3 >> 6, lane = s3 & 63;
        int m = lane & 31, c0 = kb * 16 + (lane >> 5) * 8;
        src = w3 + ((size_t)k * 32 + m) * 128 + c0;
        dst = W3F + (((size_t)k * 8 + kb) * 512) + lane * 8;
      }
      float4 a = *(const float4*)src, b4 = *(const float4*)(src + 4);
      u16 o[8] = { f2bf(a.x), f2bf(a.y), f2bf(a.z), f2bf(a.w),
                   f2bf(b4.x), f2bf(b4.y), f2bf(b4.z), f2bf(b4.w) };
      *(uint4*)dst = *(uint4*)o;
    }
  }
}

// ============ main: per-(k, b-pair), all loads coalesced frag-order ============
__global__ __launch_bounds__(256, 3) void cssr_main(
    const u16* __restrict__ W1F, const u16* __restrict__ W2F, const u16* __restrict__ W3F,
    const u16* __restrict__ xF, const float* __restrict__ protos,
    const float* __restrict__ protos1, float* __restrict__ out,
    float* __restrict__ fw, float* __restrict__ f1w)
{
  __shared__ u16 sB[2][4][4][512];      // x dbuf: [buf][ksl][nt][frag]; later h2f [8][4][512]
  __shared__ u16 h1f[4][4][512];        // [kb][nt][frag]
  __shared__ float red[8];
  u16 (*h2f)[4][512] = (u16(*)[4][512])&sB[0][0][0][0];

  const int bid = blockIdx.x;
  const int k = bid >> 5, b0 = (bid & 31) * 2;
  const int tid = threadIdx.x, w = tid >> 6, lane = tid & 63;
  const int nhalf = lane >> 5, nn = lane & 31;
  const int mt = w >> 1, ntp = w & 1;

  // ---------------- stage 1: h1 = tanh(W1[k] @ x)  M=64 N=128 K=512 ----------
  #pragma unroll
  for (int nt = 0; nt < 4; nt++) {      // preload ck=0; wave w stages ksl=w
    const u16* gp = xF + (((size_t)(b0 + (nt >> 1)) * 64 + w * 2 + (nt & 1)) * 512) + lane * 8;
    ld_lds16(gp, &sB[0][w][nt][0]);
  }
  __syncthreads();

  f32x16 acc1[2] = {};
  for (int ck = 0; ck < 8; ck++) {
    const int pb = ck & 1;
    if (ck < 7) {
      #pragma unroll
      for (int nt = 0; nt < 4; nt++) {
        const u16* gp = xF + (((size_t)(b0 + (nt >> 1)) * 64 + ((ck + 1) * 4 + w) * 2 + (nt & 1)) * 512) + lane * 8;
        ld_lds16(gp, &sB[pb ^ 1][w][nt][0]);
      }
    }
    #pragma unroll
    for (int ksl = 0; ksl < 4; ksl++) {
      s16x8 A = *(const s16x8*)(W1F + (((size_t)k * 64 + (ck * 4 + ksl) * 2 + mt) * 512) + lane * 8);
      #pragma unroll
      for (int ntl = 0; ntl < 2; ntl++) {
        s16x8 B = *(const s16x8*)&sB[pb][ksl][ntp * 2 + ntl][lane * 8];
        acc1[ntl] = MFMA32(A, B, acc1[ntl]);
      }
    }
    __syncthreads();
  }

  // handoff: C/D (m = q+8g+4*nhalf, n) -> stage2 B-frags
  #pragma unroll
  for (int ntl = 0; ntl < 2; ntl++) {
    int nt = ntp * 2 + ntl;
    #pragma unroll
    for (int g = 0; g < 4; g++) {
      u16 hv[4];
      #pragma unroll
      for (int q = 0; q < 4; q++) hv[q] = f2bf(tanh_fast(acc1[ntl][g * 4 + q]));
      int kbg = mt * 2 + (g >> 1);
      int tl  = (g & 1) * 32 + nn;
      *(u64b*)&h1f[kbg][nt][tl * 8 + nhalf * 4] = *(u64b*)hv;
    }
  }
  __syncthreads();

  // ---------------- stage 2: h2 = tanh(W2[k] @ h1)  M=128 N=128 K=64 ----------
  f32x16 acc2[2][2] = {};
  #pragma unroll
  for (int kb = 0; kb < 4; kb++) {
    s16x8 A0 = *(const s16x8*)(W2F + (((size_t)k * 16 + kb * 4 + (mt * 2 + 0)) * 512) + lane * 8);
    s16x8 A1 = *(const s16x8*)(W2F + (((size_t)k * 16 + kb * 4 + (mt * 2 + 1)) * 512) + lane * 8);
    #pragma unroll
    for (int ntl = 0; ntl < 2; ntl++) {
      s16x8 B = *(const s16x8*)&h1f[kb][ntp * 2 + ntl][lane * 8];
      acc2[0][ntl] = MFMA32(A0, B, acc2[0][ntl]);
      acc2[1][ntl] = MFMA32(A1, B, acc2[1][ntl]);
    }
  }
  // handoff into h2f (aliases sB; all stage-1 reads done at loop's last barrier)
  #pragma unroll
  for (int i = 0; i < 2; i++) {
    #pragma unroll
    for (int ntl = 0; ntl < 2; ntl++) {
      int nt = ntp * 2 + ntl;
      #pragma unroll
      for (int g = 0; g < 4; g++) {
        u16 hv[4];
        #pragma unroll
        for (int q = 0; q < 4; q++) hv[q] = f2bf(tanh_fast(acc2[i][ntl][g * 4 + q]));
        int kbg2 = (mt * 2 + i) * 2 + (g >> 1);
        int tl   = (g & 1) * 32 + nn;
        *(u64b*)&h2f[kbg2][nt][tl * 8 + nhalf * 4] = *(u64b*)hv;
      }
    }
  }
  __syncthreads();

  // ---------------- stage 3: lt = tanh(W3[k] @ h2)  M=32 N=128 K=128 ----------
  f32x16 acc3 = {};
  #pragma unroll
  for (int kb = 0; kb < 8; kb++) {
    s16x8 A = *(const s16x8*)(W3F + (((size_t)k * 8 + kb) * 512) + lane * 8);
    s16x8 B = *(const s16x8*)&h2f[kb][w][lane * 8];
    acc3 = MFMA32(A, B, acc3);
  }

  // ---------------- distances, clip, logits, f / f1 ----------------
  const int b = b0 + (w >> 1);
  const int p = (w & 1) * 32 + nn;
  const float* pr  = protos  + (size_t)k * 2048;
  const float* pr1 = protos1 + (size_t)k * 2048;
  float d2 = 0.f, d21 = 0.f;
  #pragma unroll
  for (int g = 0; g < 4; g++) {
    #pragma unroll
    for (int q = 0; q < 4; q++) {
      int m = q + 8 * g + 4 * nhalf;
      float lt = tanh_fast(acc3[g * 4 + q]);
      float d = lt - pr [m * 64 + p];  d2  += d * d;
      float e = lt - pr1[m * 64 + p];  d21 += e * e;
    }
  }
  d2 += __shfl_xor(d2, 32); d21 += __shfl_xor(d21, 32);
  float er  = fminf(fmaxf(d2  * -0.1f, -100.f), 100.f);
  float er1 = fminf(fmaxf(d21 * -0.1f, -100.f), 100.f);
  if (nhalf == 0) {
    out[(size_t)b * 6400 + k * 64 + p]          = er;
    out[409600 + (size_t)b * 6400 + k * 64 + p] = er1;
  }
  float s = er, s1 = er1;
  s += __shfl_xor(s, 1);  s1 += __shfl_xor(s1, 1);
  s += __shfl_xor(s, 2);  s1 += __shfl_xor(s1, 2);
  s += __shfl_xor(s, 4);  s1 += __shfl_xor(s1, 4);
  s += __shfl_xor(s, 8);  s1 += __shfl_xor(s1, 8);
  s += __shfl_xor(s, 16); s1 += __shfl_xor(s1, 16);
  if (lane == 0) { red[w] = s; red[4 + w] = s1; }
  __syncthreads();
  if (tid < 2)      fw [k * 64 + b0 + tid]       = red[tid * 2] + red[tid * 2 + 1];
  else if (tid < 4) f1w[k * 64 + b0 + (tid - 2)] = red[4 + (tid - 2) * 2] + red[5 + (tid - 2) * 2];
}

// ============ finalize: two phases (parallel per-k, then tiny reduce) ============
__global__ void finalize1(const float* __restrict__ f, const float* __restrict__ f1,
                          const int* __restrict__ ycls, float* __restrict__ pk,
                          float* __restrict__ qk) {
  const int k = blockIdx.x, b = threadIdx.x;
  float fv = f[k * 64 + b], f1v = f1[k * 64 + b];
  bool eq = (ycls[b] == k);
  bool cb = (!eq) && (fv < 10000.f);
  float s1 = eq ? f1v : 0.f, ne = eq ? 1.f : 0.f;
  float s  = cb ? fv  : 0.f, nc = cb ? 1.f : 0.f;
  #pragma unroll
  for (int o = 1; o < 64; o <<= 1) {
    s1 += __shfl_xor(s1, o); ne += __shfl_xor(ne, o);
    s  += __shfl_xor(s,  o); nc += __shfl_xor(nc, o);
  }
  if (b == 0) {
    pk[k] = ne > 0.f ? s1 / ne : 0.f;
    qk[k] = nc > 0.f ? s  / nc : 0.f;
  }
}

__global__ void finalize2(const float* __restrict__ pk, const float* __restrict__ qk,
                          float* __restrict__ out2) {
  __shared__ float rp[128], rq[128];
  int t = threadIdx.x;
  rp[t] = (t < KCLS) ? pk[t] : 0.f;
  rq[t] = (t < KCLS) ? qk[t] : 0.f;
  __syncthreads();
  for (int off = 64; off > 0; off >>= 1) {
    if (t < off) { rp[t] += rp[t + off]; rq[t] += rq[t + off]; }
    __syncthreads();
  }
  if (t == 0) { out2[0] = rp[0]; out2[1] = rq[0]; }
}

extern "C" void kernel_launch(void* const* d_in, const int* in_sizes, int n_in,
                              void* d_out, int out_size, void* d_ws, size_t ws_size,
                              hipStream_t stream) {
  const float* x     = (const float*)d_in[0];
  const int*   ycls  = (const int*)d_in[1];
  const float* W1    = (const float*)d_in[4];
  const float* W2    = (const float*)d_in[5];
  const float* W3    = (const float*)d_in[6];
  const float* prot  = (const float*)d_in[7];
  const float* prot1 = (const float*)d_in[8];
  float* out = (float*)d_out;

  char* ws = (char*)d_ws;
  u16*  xFb = (u16*)(ws);                        // 4,194,304 B
  u16*  W1F = (u16*)(ws + 4194304);              // 6,553,600 B
  u16*  W2F = (u16*)(ws + 10747904);             // 1,638,400 B
  u16*  W3F = (u16*)(ws + 12386304);             //   819,200 B
  float* fw  = (float*)(ws + 13205504);          // 25,600 B
  float* f1w = (float*)(ws + 13231104);          // 25,600 B
  float* pk  = (float*)(ws + 13256704);          // 400 B
  float* qk  = (float*)(ws + 13257104);          // 400 B

  prep<<<264, 256, 0, stream>>>(x, W1, W2, W3, xFb, W1F, W2F, W3F);
  cssr_main<<<KCLS * 32, 256, 0, stream>>>(W1F, W2F, W3F, xFb, prot, prot1, out, fw, f1w);
  finalize1<<<KCLS, 64, 0, stream>>>(fw, f1w, ycls, pk, qk);
  finalize2<<<1, 128, 0, stream>>>(pk, qk, out + 819200);
}

// Round 4
// 151.033 us; speedup vs baseline: 1.5891x; 1.0710x over previous
//
#include <hip/hip_runtime.h>

typedef short  s16x8  __attribute__((ext_vector_type(8)));
typedef float  f32x16 __attribute__((ext_vector_type(16)));
typedef unsigned short u16;
typedef unsigned long long u64b;

#define MFMA32(a,b,c) __builtin_amdgcn_mfma_f32_32x32x16_bf16((a),(b),(c),0,0,0)
#define KCLS 100

__device__ __forceinline__ u16 f2bf(float f) {
  // truncation: ~1 op/val; error budget is huge (thresholds >> bf16 ulp effects)
  return (u16)(__builtin_bit_cast(unsigned, f) >> 16);
}

__device__ __forceinline__ float tanh_fast(float x) {
  float e = __builtin_amdgcn_exp2f(x * 2.8853900817779268f);
  return 1.0f - 2.0f * __builtin_amdgcn_rcpf(e + 1.0f);
}

__device__ __forceinline__ void ld_lds16(const void* g, void* l) {
  __builtin_amdgcn_global_load_lds(
      (const __attribute__((address_space(1))) unsigned char*)g,
      (__attribute__((address_space(3))) unsigned char*)l, 16, 0, 0);
}

// ============ prep: emit fragment-ordered bf16 tensors (wide grid) ============
// Fragment = 1 KB: [lane64][8 bf16]; lane&31 = row/col-in-tile, lane>>5 = k-half.
// xF  [b][frag = gks*2+ph]   gks in [0,32): p = ph*32+(lane&31), c = gks*16+(lane>>5)*8+j
// W1F [k][frag = gks*2+mt]   m = mt*32+(lane&31), c as above
// W2F [k][frag = kb*4+m4]    m = m4*32+(lane&31), c = kb*16+(lane>>5)*8+j
// W3F [k][frag = kb]         m = lane&31,         c = kb*16+(lane>>5)*8+j
__global__ void prep(const float* __restrict__ x, const float* __restrict__ w1,
                     const float* __restrict__ w2, const float* __restrict__ w3,
                     u16* __restrict__ xF, u16* __restrict__ W1F,
                     u16* __restrict__ W2F, u16* __restrict__ W3F,
                     float* __restrict__ out2) {
  __shared__ float tile[64][65];
  const int bid = blockIdx.x, t = threadIdx.x;
  if (bid == 0 && t < 2) out2[t] = 0.f;          // zero pull/push accumulators
  if (bid < 512) {                                // ---- x: block = (b, ck) ----
    const int b = bid >> 3, ck = bid & 7;
    #pragma unroll
    for (int j = 0; j < 4; j++) {                 // coalesced fp32 tile (64c x 64p)
      int e4 = j * 1024 + t * 4;
      int c = e4 >> 6, p0 = e4 & 63;
      float4 v = *(const float4*)(x + ((size_t)b * 512 + ck * 64 + c) * 64 + p0);
      tile[c][p0] = v.x; tile[c][p0 + 1] = v.y; tile[c][p0 + 2] = v.z; tile[c][p0 + 3] = v.w;
    }
    __syncthreads();
    #pragma unroll
    for (int i = 0; i < 2; i++) {                 // 512 16B-slots
      int s = i * 256 + t;
      int ksl = s >> 7, ph = (s >> 6) & 1, lane = s & 63;
      int cb = ksl * 16 + (lane >> 5) * 8, pp = ph * 32 + (lane & 31);
      u16 o[8];
      #pragma unroll
      for (int jj = 0; jj < 8; jj++) o[jj] = f2bf(tile[cb + jj][pp]);
      *(uint4*)(xF + (((size_t)b * 64 + (ck * 4 + ksl) * 2 + ph) * 512) + lane * 8) = *(uint4*)o;
    }
  } else if (bid < 1312) {                        // ---- W1: 6400 frags ----
    int base = (bid - 512) * 512;
    #pragma unroll
    for (int i = 0; i < 2; i++) {
      int s = base + i * 256 + t;
      int frag = s >> 6, lane = s & 63;
      int k = frag >> 6, fr = frag & 63;
      int m = (fr & 1) * 32 + (lane & 31);
      int c0 = (fr >> 1) * 16 + (lane >> 5) * 8;
      const float* src = w1 + ((size_t)k * 64 + m) * 512 + c0;
      float4 a = *(const float4*)src, b4 = *(const float4*)(src + 4);
      u16 o[8] = { f2bf(a.x), f2bf(a.y), f2bf(a.z), f2bf(a.w),
                   f2bf(b4.x), f2bf(b4.y), f2bf(b4.z), f2bf(b4.w) };
      *(uint4*)(W1F + ((size_t)frag * 512) + lane * 8) = *(uint4*)o;
    }
  } else if (bid < 1512) {                        // ---- W2: 1600 frags ----
    int base = (bid - 1312) * 512;
    #pragma unroll
    for (int i = 0; i < 2; i++) {
      int s = base + i * 256 + t;
      int frag = s >> 6, lane = s & 63;
      int k = frag >> 4, fr = frag & 15;
      int m = (fr & 3) * 32 + (lane & 31);
      int c0 = (fr >> 2) * 16 + (lane >> 5) * 8;
      const float* src = w2 + ((size_t)k * 128 + m) * 64 + c0;
      float4 a = *(const float4*)src, b4 = *(const float4*)(src + 4);
      u16 o[8] = { f2bf(a.x), f2bf(a.y), f2bf(a.z), f2bf(a.w),
                   f2bf(b4.x), f2bf(b4.y), f2bf(b4.z), f2bf(b4.w) };
      *(uint4*)(W2F + ((size_t)frag * 512) + lane * 8) = *(uint4*)o;
    }
  } else {                                        // ---- W3: 800 frags ----
    int base = (bid - 1512) * 512;
    #pragma unroll
    for (int i = 0; i < 2; i++) {
      int s = base + i * 256 + t;
      int frag = s >> 6, lane = s & 63;
      int k = frag >> 3, kb = frag & 7;
      int m = lane & 31;
      int c0 = kb * 16 + (lane >> 5) * 8;
      const float* src = w3 + ((size_t)k * 32 + m) * 128 + c0;
      float4 a = *(const float4*)src, b4 = *(const float4*)(src + 4);
      u16 o[8] = { f2bf(a.x), f2bf(a.y), f2bf(a.z), f2bf(a.w),
                   f2bf(b4.x), f2bf(b4.y), f2bf(b4.z), f2bf(b4.w) };
      *(uint4*)(W3F + ((size_t)frag * 512) + lane * 8) = *(uint4*)o;
    }
  }
}

// ============ main: per-(k, b-pair); 32 KB LDS (h2f overlays dbuf+h1f) ============
__global__ __launch_bounds__(256, 4) void cssr_main(
    const u16* __restrict__ W1F, const u16* __restrict__ W2F, const u16* __restrict__ W3F,
    const u16* __restrict__ xF, const float* __restrict__ protos,
    const float* __restrict__ protos1, float* __restrict__ out,
    float* __restrict__ fw, float* __restrict__ f1w)
{
  __shared__ u16 pool[16384];             // 32 KB
  __shared__ float red[8];
  u16 (*sB)[2][4][512] = (u16(*)[2][4][512])pool;          // dbuf [2][2ksl][4nt][512]: 16 KB
  u16 (*h1f)[4][512]   = (u16(*)[4][512])(pool + 8192);    // [4kb][4nt][512]: 16 KB
  u16 (*h2f)[4][512]   = (u16(*)[4][512])pool;             // [8kb][4nt][512]: 32 KB overlay

  const int bid = blockIdx.x;
  const int k = bid >> 5, b0 = (bid & 31) * 2;
  const int tid = threadIdx.x, w = tid >> 6, lane = tid & 63;
  const int nhalf = lane >> 5, nn = lane & 31;
  const int mt = w >> 1, ntp = w & 1;

  // ---------------- stage 1: h1 = tanh(W1[k] @ x)  M=64 N=128 K=512 ----------
  // 16 chunks of 32 c (2 k-slices each), double-buffered. Wave w stages frags 2w,2w+1.
  #pragma unroll
  for (int i = 0; i < 2; i++) {
    int f = 2 * w + i, ksl = f >> 2, nt = f & 3;
    const u16* gp = xF + (((size_t)(b0 + (nt >> 1)) * 64 + ksl * 2 + (nt & 1)) * 512) + lane * 8;
    ld_lds16(gp, &sB[0][ksl][nt][0]);
  }
  __syncthreads();

  f32x16 acc1[2] = {};
  for (int ch = 0; ch < 16; ch++) {
    const int pb = ch & 1;
    if (ch < 15) {
      #pragma unroll
      for (int i = 0; i < 2; i++) {
        int f = 2 * w + i, ksl = f >> 2, nt = f & 3;
        int g = (ch + 1) * 2 + ksl;
        const u16* gp = xF + (((size_t)(b0 + (nt >> 1)) * 64 + g * 2 + (nt & 1)) * 512) + lane * 8;
        ld_lds16(gp, &sB[pb ^ 1][ksl][nt][0]);
      }
    }
    #pragma unroll
    for (int ksl = 0; ksl < 2; ksl++) {
      int g = ch * 2 + ksl;
      s16x8 A = *(const s16x8*)(W1F + (((size_t)k * 64 + g * 2 + mt) * 512) + lane * 8);
      #pragma unroll
      for (int ntl = 0; ntl < 2; ntl++) {
        s16x8 B = *(const s16x8*)&sB[pb][ksl][ntp * 2 + ntl][lane * 8];
        acc1[ntl] = MFMA32(A, B, acc1[ntl]);
      }
    }
    __syncthreads();
  }

  // handoff: C/D (m = q+8g+4*nhalf, n) -> stage2 B-frags in h1f
  #pragma unroll
  for (int ntl = 0; ntl < 2; ntl++) {
    int nt = ntp * 2 + ntl;
    #pragma unroll
    for (int g = 0; g < 4; g++) {
      u16 hv[4];
      #pragma unroll
      for (int q = 0; q < 4; q++) hv[q] = f2bf(tanh_fast(acc1[ntl][g * 4 + q]));
      int kbg = mt * 2 + (g >> 1);
      int tl  = (g & 1) * 32 + nn;
      *(u64b*)&h1f[kbg][nt][tl * 8 + nhalf * 4] = *(u64b*)hv;
    }
  }
  __syncthreads();

  // ---------------- stage 2: h2 = tanh(W2[k] @ h1)  M=128 N=128 K=64 ----------
  f32x16 acc2[2][2] = {};
  #pragma unroll
  for (int kb = 0; kb < 4; kb++) {
    s16x8 A0 = *(const s16x8*)(W2F + (((size_t)k * 16 + kb * 4 + (mt * 2 + 0)) * 512) + lane * 8);
    s16x8 A1 = *(const s16x8*)(W2F + (((size_t)k * 16 + kb * 4 + (mt * 2 + 1)) * 512) + lane * 8);
    #pragma unroll
    for (int ntl = 0; ntl < 2; ntl++) {
      s16x8 B = *(const s16x8*)&h1f[kb][ntp * 2 + ntl][lane * 8];
      acc2[0][ntl] = MFMA32(A0, B, acc2[0][ntl]);
      acc2[1][ntl] = MFMA32(A1, B, acc2[1][ntl]);
    }
  }
  __syncthreads();   // all h1f reads done before h2f (overlaying) is written

  // handoff into h2f (overlays sB + h1f)
  #pragma unroll
  for (int i = 0; i < 2; i++) {
    #pragma unroll
    for (int ntl = 0; ntl < 2; ntl++) {
      int nt = ntp * 2 + ntl;
      #pragma unroll
      for (int g = 0; g < 4; g++) {
        u16 hv[4];
        #pragma unroll
        for (int q = 0; q < 4; q++) hv[q] = f2bf(tanh_fast(acc2[i][ntl][g * 4 + q]));
        int kbg2 = (mt * 2 + i) * 2 + (g >> 1);
        int tl   = (g & 1) * 32 + nn;
        *(u64b*)&h2f[kbg2][nt][tl * 8 + nhalf * 4] = *(u64b*)hv;
      }
    }
  }
  __syncthreads();

  // ---------------- stage 3: lt = tanh(W3[k] @ h2)  M=32 N=128 K=128 ----------
  f32x16 acc3 = {};
  #pragma unroll
  for (int kb = 0; kb < 8; kb++) {
    s16x8 A = *(const s16x8*)(W3F + (((size_t)k * 8 + kb) * 512) + lane * 8);
    s16x8 B = *(const s16x8*)&h2f[kb][w][lane * 8];
    acc3 = MFMA32(A, B, acc3);
  }

  // ---------------- distances, clip, logits, f / f1 ----------------
  const int b = b0 + (w >> 1);
  const int p = (w & 1) * 32 + nn;
  const float* pr  = protos  + (size_t)k * 2048;
  const float* pr1 = protos1 + (size_t)k * 2048;
  float d2 = 0.f, d21 = 0.f;
  #pragma unroll
  for (int g = 0; g < 4; g++) {
    #pragma unroll
    for (int q = 0; q < 4; q++) {
      int m = q + 8 * g + 4 * nhalf;
      float lt = tanh_fast(acc3[g * 4 + q]);
      float d = lt - pr [m * 64 + p];  d2  += d * d;
      float e = lt - pr1[m * 64 + p];  d21 += e * e;
    }
  }
  d2 += __shfl_xor(d2, 32); d21 += __shfl_xor(d21, 32);
  float er  = fminf(fmaxf(d2  * -0.1f, -100.f), 100.f);
  float er1 = fminf(fmaxf(d21 * -0.1f, -100.f), 100.f);
  if (nhalf == 0) {
    out[(size_t)b * 6400 + k * 64 + p]          = er;
    out[409600 + (size_t)b * 6400 + k * 64 + p] = er1;
  }
  float s = er, s1 = er1;
  s += __shfl_xor(s, 1);  s1 += __shfl_xor(s1, 1);
  s += __shfl_xor(s, 2);  s1 += __shfl_xor(s1, 2);
  s += __shfl_xor(s, 4);  s1 += __shfl_xor(s1, 4);
  s += __shfl_xor(s, 8);  s1 += __shfl_xor(s1, 8);
  s += __shfl_xor(s, 16); s1 += __shfl_xor(s1, 16);
  if (lane == 0) { red[w] = s; red[4 + w] = s1; }
  __syncthreads();
  if (tid < 2)      fw [k * 64 + b0 + tid]       = red[tid * 2] + red[tid * 2 + 1];
  else if (tid < 4) f1w[k * 64 + b0 + (tid - 2)] = red[4 + (tid - 2) * 2] + red[5 + (tid - 2) * 2];
}

// ============ finalize: one kernel, atomicAdd into out2 (zeroed in prep) ============
__global__ void finalize(const float* __restrict__ f, const float* __restrict__ f1,
                         const int* __restrict__ ycls, float* __restrict__ out2) {
  const int k = blockIdx.x, b = threadIdx.x;
  float fv = f[k * 64 + b], f1v = f1[k * 64 + b];
  bool eq = (ycls[b] == k);
  bool cb = (!eq) && (fv < 10000.f);
  float s1 = eq ? f1v : 0.f, ne = eq ? 1.f : 0.f;
  float s  = cb ? fv  : 0.f, nc = cb ? 1.f : 0.f;
  #pragma unroll
  for (int o = 1; o < 64; o <<= 1) {
    s1 += __shfl_xor(s1, o); ne += __shfl_xor(ne, o);
    s  += __shfl_xor(s,  o); nc += __shfl_xor(nc, o);
  }
  if (b == 0) {
    if (ne > 0.f) atomicAdd(&out2[0], s1 / ne);
    if (nc > 0.f) atomicAdd(&out2[1], s / nc);
  }
}

extern "C" void kernel_launch(void* const* d_in, const int* in_sizes, int n_in,
                              void* d_out, int out_size, void* d_ws, size_t ws_size,
                              hipStream_t stream) {
  const float* x     = (const float*)d_in[0];
  const int*   ycls  = (const int*)d_in[1];
  const float* W1    = (const float*)d_in[4];
  const float* W2    = (const float*)d_in[5];
  const float* W3    = (const float*)d_in[6];
  const float* prot  = (const float*)d_in[7];
  const float* prot1 = (const float*)d_in[8];
  float* out = (float*)d_out;

  char* ws = (char*)d_ws;
  u16*  xFb = (u16*)(ws);                        // 4,194,304 B
  u16*  W1F = (u16*)(ws + 4194304);              // 6,553,600 B
  u16*  W2F = (u16*)(ws + 10747904);             // 1,638,400 B
  u16*  W3F = (u16*)(ws + 12386304);             //   819,200 B
  float* fw  = (float*)(ws + 13205504);          // 25,600 B
  float* f1w = (float*)(ws + 13231104);          // 25,600 B

  prep<<<1612, 256, 0, stream>>>(x, W1, W2, W3, xFb, W1F, W2F, W3F, out + 819200);
  cssr_main<<<KCLS * 32, 256, 0, stream>>>(W1F, W2F, W3F, xFb, prot, prot1, out, fw, f1w);
  finalize<<<KCLS, 64, 0, stream>>>(fw, f1w, ycls, out + 819200);
}